// Round 1
// baseline (2798.183 us; speedup 1.0000x reference)
//
#include <hip/hip_runtime.h>
#include <hip/hip_bf16.h>

// 2-layer GIN:
//   agg = segment_sum(h[src], dst);  h' = relu((h + agg) @ W + b)
// N_NODES=100000, N_EDGES=1600000, D=64, fp32.

#define D 64
#define ROWS_PER_BLOCK 32

// agg := h   (grid-stride float4 copy)
__global__ void copy_f4(const float4* __restrict__ in, float4* __restrict__ out, int n4) {
    int i = blockIdx.x * blockDim.x + threadIdx.x;
    if (i < n4) out[i] = in[i];
}

// 16 threads per edge; each thread handles a float4 chunk of the 64-dim row.
__global__ void scatter_add(const float4* __restrict__ h, const int* __restrict__ src,
                            const int* __restrict__ dst, float* __restrict__ agg,
                            int n_edges) {
    int t = blockIdx.x * blockDim.x + threadIdx.x;
    int e = t >> 4;
    if (e >= n_edges) return;
    int c = t & 15;
    int s = src[e];
    int d = dst[e];
    float4 v = h[(size_t)s * (D / 4) + c];
    float* p = agg + (size_t)d * D + c * 4;
    unsafeAtomicAdd(p + 0, v.x);
    unsafeAtomicAdd(p + 1, v.y);
    unsafeAtomicAdd(p + 2, v.z);
    unsafeAtomicAdd(p + 3, v.w);
}

// out = relu(hs @ W + b), hs = (h + agg) already summed.
// Block: 256 threads = 4 waves; each wave handles 8 rows, lane = output col.
__global__ __launch_bounds__(256) void gin_mlp(const float* __restrict__ hs,
                                               const float* __restrict__ W,
                                               const float* __restrict__ b,
                                               float* __restrict__ out,
                                               int n_nodes) {
    __shared__ float Wl[D * D];       // 16 KiB
    __shared__ float bl[D];
    __shared__ float rows[ROWS_PER_BLOCK][D];  // 8 KiB

    int tid = threadIdx.x;

    // Stage W (4096 floats = 1024 float4; 4 per thread)
    const float4* W4 = (const float4*)W;
    float4* Wl4 = (float4*)Wl;
#pragma unroll
    for (int i = 0; i < 4; ++i) Wl4[tid + 256 * i] = W4[tid + 256 * i];
    if (tid < D / 4) ((float4*)bl)[tid] = ((const float4*)b)[tid];

    // Stage 32 rows (2048 floats = 512 float4; 2 per thread)
    size_t row0 = (size_t)blockIdx.x * ROWS_PER_BLOCK;
    const float4* hs4 = (const float4*)(hs + row0 * D);
    float4* rows4 = (float4*)rows;
#pragma unroll
    for (int i = 0; i < 2; ++i) rows4[tid + 256 * i] = hs4[tid + 256 * i];

    __syncthreads();

    int lane = tid & 63;   // output column
    int w = tid >> 6;      // wave id: rows w*8 .. w*8+7

    float acc[8];
#pragma unroll
    for (int r = 0; r < 8; ++r) acc[r] = bl[lane];

#pragma unroll
    for (int k = 0; k < D; ++k) {
        float wv = Wl[k * D + lane];   // stride-1 across lanes: conflict-free
#pragma unroll
        for (int r = 0; r < 8; ++r)
            acc[r] = fmaf(rows[w * 8 + r][k], wv, acc[r]);  // LDS broadcast
    }

#pragma unroll
    for (int r = 0; r < 8; ++r) {
        float v = acc[r] > 0.0f ? acc[r] : 0.0f;
        out[(row0 + (size_t)w * 8 + r) * D + lane] = v;
    }
}

extern "C" void kernel_launch(void* const* d_in, const int* in_sizes, int n_in,
                              void* d_out, int out_size, void* d_ws, size_t ws_size,
                              hipStream_t stream) {
    const float* x   = (const float*)d_in[0];
    const int*   src = (const int*)d_in[1];
    const int*   dst = (const int*)d_in[2];
    const float* W1  = (const float*)d_in[3];
    const float* b1  = (const float*)d_in[4];
    const float* W2  = (const float*)d_in[5];
    const float* b2  = (const float*)d_in[6];
    float* out = (float*)d_out;

    const int n_nodes = in_sizes[0] / D;
    const int n_edges = in_sizes[1];

    float* agg = (float*)d_ws;                       // [n_nodes, 64]
    float* h1  = agg + (size_t)n_nodes * D;          // [n_nodes, 64]

    const int n4 = n_nodes * (D / 4);                // float4 count per feature matrix
    const int copy_blocks = (n4 + 255) / 256;
    const int scat_threads = n_edges * 16;
    const int scat_blocks = (scat_threads + 255) / 256;
    const int mlp_blocks = (n_nodes + ROWS_PER_BLOCK - 1) / ROWS_PER_BLOCK;

    // ---- layer 1 ----
    copy_f4<<<copy_blocks, 256, 0, stream>>>((const float4*)x, (float4*)agg, n4);
    scatter_add<<<scat_blocks, 256, 0, stream>>>((const float4*)x, src, dst, agg, n_edges);
    gin_mlp<<<mlp_blocks, 256, 0, stream>>>(agg, W1, b1, h1, n_nodes);

    // ---- layer 2 ----
    copy_f4<<<copy_blocks, 256, 0, stream>>>((const float4*)h1, (float4*)agg, n4);
    scatter_add<<<scat_blocks, 256, 0, stream>>>((const float4*)h1, src, dst, agg, n_edges);
    gin_mlp<<<mlp_blocks, 256, 0, stream>>>(agg, W2, b2, out, n_nodes);
}

// Round 2
// 416.835 us; speedup vs baseline: 6.7129x; 6.7129x over previous
//
#include <hip/hip_runtime.h>
#include <hip/hip_bf16.h>

// 2-layer GIN, pull-mode aggregation via per-launch CSR build.
//   agg = segment_sum(h[src], dst) + h;  h' = relu(agg @ W + b)
// N_NODES=100000, N_EDGES=1600000, D=64, fp32.

#define D 64
#define ROWS_PER_BLOCK 32
#define SCAN_CHUNK 2048   // 256 threads x 8 elems

// ---------------- CSR build ----------------

__global__ void zero_int(int* __restrict__ p, int n) {
    int i = blockIdx.x * blockDim.x + threadIdx.x;
    if (i < n) p[i] = 0;
}

__global__ void hist_dst(const int* __restrict__ dst, int* __restrict__ deg, int n_edges) {
    int e = blockIdx.x * blockDim.x + threadIdx.x;
    if (e < n_edges) atomicAdd(&deg[dst[e]], 1);
}

// Per-chunk exclusive scan; chunk totals to blocksums.
__global__ __launch_bounds__(256) void scan_chunk(const int* __restrict__ deg,
                                                  int* __restrict__ offs,
                                                  int* __restrict__ blocksums, int n) {
    __shared__ int tsum[256];
    int base = blockIdx.x * SCAN_CHUNK;
    int tid = threadIdx.x;
    int v[8];
    int s = 0;
#pragma unroll
    for (int i = 0; i < 8; ++i) {
        int idx = base + tid * 8 + i;
        v[i] = (idx < n) ? deg[idx] : 0;
        s += v[i];
    }
    tsum[tid] = s;
    __syncthreads();
    // Hillis-Steele inclusive scan over 256 thread sums
    for (int off = 1; off < 256; off <<= 1) {
        int val = (tid >= off) ? tsum[tid - off] : 0;
        __syncthreads();
        tsum[tid] += val;
        __syncthreads();
    }
    int run = (tid == 0) ? 0 : tsum[tid - 1];
#pragma unroll
    for (int i = 0; i < 8; ++i) {
        int idx = base + tid * 8 + i;
        if (idx < n) offs[idx] = run;
        run += v[i];
    }
    if (tid == 255) blocksums[blockIdx.x] = tsum[255];
}

__global__ void scan_bsums(int* __restrict__ bs, int nb) {
    if (threadIdx.x == 0 && blockIdx.x == 0) {
        int run = 0;
        for (int i = 0; i < nb; ++i) { int t = bs[i]; bs[i] = run; run += t; }
    }
}

__global__ void finalize_offsets(int* __restrict__ offs, const int* __restrict__ bs,
                                 int* __restrict__ cursor, int n, int n_edges) {
    int i = blockIdx.x * blockDim.x + threadIdx.x;
    if (i < n) {
        int v = offs[i] + bs[i / SCAN_CHUNK];
        offs[i] = v;
        cursor[i] = v;
    }
    if (i == 0) offs[n] = n_edges;
}

__global__ void bucket_edges(const int* __restrict__ src, const int* __restrict__ dst,
                             int* __restrict__ cursor, int* __restrict__ esrc, int n_edges) {
    int e = blockIdx.x * blockDim.x + threadIdx.x;
    if (e < n_edges) {
        int pos = atomicAdd(&cursor[dst[e]], 1);
        esrc[pos] = src[e];
    }
}

// ---------------- per-layer kernels ----------------

// Pull aggregation: 16 threads per dst node, one float4 chunk each.
// acc starts at h[n] (folds the (1+eps)*h self-term, eps=0).
__global__ void gin_agg(const float4* __restrict__ h, const int* __restrict__ offs,
                        const int* __restrict__ esrc, float4* __restrict__ agg,
                        int n_nodes) {
    int t = blockIdx.x * blockDim.x + threadIdx.x;
    int n = t >> 4;
    if (n >= n_nodes) return;
    int c = t & 15;
    int beg = offs[n];
    int end = offs[n + 1];
    float4 acc = h[(size_t)n * 16 + c];
    for (int i = beg; i < end; ++i) {
        int s = esrc[i];
        float4 v = h[(size_t)s * 16 + c];
        acc.x += v.x; acc.y += v.y; acc.z += v.z; acc.w += v.w;
    }
    agg[(size_t)n * 16 + c] = acc;
}

// out = relu(hs @ W + b). Safe in-place (hs == out): rows staged in LDS first,
// each block only touches its own 32 rows.
__global__ __launch_bounds__(256) void gin_mlp(const float* __restrict__ hs,
                                               const float* __restrict__ W,
                                               const float* __restrict__ b,
                                               float* __restrict__ out,
                                               int n_nodes) {
    __shared__ float Wl[D * D];                 // 16 KiB
    __shared__ float bl[D];
    __shared__ float rows[ROWS_PER_BLOCK][D];   // 8 KiB

    int tid = threadIdx.x;

    const float4* W4 = (const float4*)W;
    float4* Wl4 = (float4*)Wl;
#pragma unroll
    for (int i = 0; i < 4; ++i) Wl4[tid + 256 * i] = W4[tid + 256 * i];
    if (tid < D / 4) ((float4*)bl)[tid] = ((const float4*)b)[tid];

    size_t row0 = (size_t)blockIdx.x * ROWS_PER_BLOCK;
    const float4* hs4 = (const float4*)(hs + row0 * D);
    float4* rows4 = (float4*)rows;
#pragma unroll
    for (int i = 0; i < 2; ++i) rows4[tid + 256 * i] = hs4[tid + 256 * i];

    __syncthreads();

    int lane = tid & 63;   // output column
    int w = tid >> 6;      // wave id: rows w*8 .. w*8+7

    float acc[8];
#pragma unroll
    for (int r = 0; r < 8; ++r) acc[r] = bl[lane];

#pragma unroll
    for (int k = 0; k < D; ++k) {
        float wv = Wl[k * D + lane];
#pragma unroll
        for (int r = 0; r < 8; ++r)
            acc[r] = fmaf(rows[w * 8 + r][k], wv, acc[r]);
    }

#pragma unroll
    for (int r = 0; r < 8; ++r) {
        float v = acc[r] > 0.0f ? acc[r] : 0.0f;
        out[(row0 + (size_t)w * 8 + r) * D + lane] = v;
    }
}

extern "C" void kernel_launch(void* const* d_in, const int* in_sizes, int n_in,
                              void* d_out, int out_size, void* d_ws, size_t ws_size,
                              hipStream_t stream) {
    const float* x   = (const float*)d_in[0];
    const int*   src = (const int*)d_in[1];
    const int*   dst = (const int*)d_in[2];
    const float* W1  = (const float*)d_in[3];
    const float* b1  = (const float*)d_in[4];
    const float* W2  = (const float*)d_in[5];
    const float* b2  = (const float*)d_in[6];
    float* out = (float*)d_out;

    const int n_nodes = in_sizes[0] / D;
    const int n_edges = in_sizes[1];

    // workspace layout (16B-aligned base): A | offs | cursor | bsums | esrc
    float* A      = (float*)d_ws;                        // [n_nodes, 64] = 25.6 MB
    int*   offs   = (int*)(A + (size_t)n_nodes * D);     // n_nodes+1
    int*   cursor = offs + (n_nodes + 1);                // n_nodes
    int*   bsums  = cursor + n_nodes;                    // scan block sums
    const int n_chunks = (n_nodes + SCAN_CHUNK - 1) / SCAN_CHUNK;
    int*   esrc   = bsums + ((n_chunks + 3) & ~3);       // n_edges, 16B-aligned-ish

    const int eb = (n_edges + 255) / 256;
    const int nb = (n_nodes + 255) / 256;
    const int agg_blocks = (n_nodes * 16 + 255) / 256;
    const int mlp_blocks = (n_nodes + ROWS_PER_BLOCK - 1) / ROWS_PER_BLOCK;

    // ---- CSR build (deg reuses cursor buffer before it becomes cursor) ----
    zero_int<<<nb, 256, 0, stream>>>(cursor, n_nodes);
    hist_dst<<<eb, 256, 0, stream>>>(dst, cursor, n_edges);
    scan_chunk<<<n_chunks, 256, 0, stream>>>(cursor, offs, bsums, n_nodes);
    scan_bsums<<<1, 64, 0, stream>>>(bsums, n_chunks);
    finalize_offsets<<<nb, 256, 0, stream>>>(offs, bsums, cursor, n_nodes, n_edges);
    bucket_edges<<<eb, 256, 0, stream>>>(src, dst, cursor, esrc, n_edges);

    // ---- layer 1: agg(x) -> A, mlp in-place A -> A (= h1) ----
    gin_agg<<<agg_blocks, 256, 0, stream>>>((const float4*)x, offs, esrc, (float4*)A, n_nodes);
    gin_mlp<<<mlp_blocks, 256, 0, stream>>>(A, W1, b1, A, n_nodes);

    // ---- layer 2: agg(h1) -> out, mlp in-place out -> out ----
    gin_agg<<<agg_blocks, 256, 0, stream>>>((const float4*)A, offs, esrc, (float4*)out, n_nodes);
    gin_mlp<<<mlp_blocks, 256, 0, stream>>>(out, W2, b2, out, n_nodes);
}